// Round 2
// 853.111 us; speedup vs baseline: 1.0022x; 1.0022x over previous
//
#include <hip/hip_runtime.h>
#include <math.h>

// Problem constants (reference: B=64, H=1024, I=1024, fp32 everywhere)
#define BB 64
#define HH 1024
#define II 1024

// Flat output offsets (floats), concatenated in reference return order:
// (new_cell[B,H], Z_new[B,H,I], F_new[B,H,I], wz_new[B,H], wf_new[B,H], bz_new[B,H], bf_new[B,H])
#define OFF_CELL 0
#define OFF_Z    ((size_t)BB * HH)                       // 65536
#define OFF_F    (OFF_Z + (size_t)BB * HH * II)          // 67174400
#define OFF_WZ   (OFF_F + (size_t)BB * HH * II)          // 134283264
#define OFF_WF   (OFF_WZ + (size_t)BB * HH)              // 134348800
#define OFF_BZ   (OFF_WF + (size_t)BB * HH)              // 134414336
#define OFF_BF   (OFF_BZ + (size_t)BB * HH)              // 134479872

// Native vector type: __builtin_nontemporal_load/store requires scalar,
// pointer, or NATIVE vector types — HIP's float4 (HIP_vector_type struct)
// is rejected. ext_vector_type(4) float compiles to the same dwordx4 access.
typedef float f32x4 __attribute__((ext_vector_type(4)));

// One block per (b,h) row. 256 threads x f32x4 = 1024 = I elements.
//
// v2 changes vs previous best (854.1 us):
//  - Z/F streaming loads hoisted to kernel entry (before the shfl/LDS/barrier
//    gate phase): the compiler cannot hoist global loads across __syncthreads,
//    so previously each block issued its 8 KB of HBM loads only AFTER an
//    L2-latency-bound reduction + 2 barriers. Now the ~900-cycle HBM latency
//    hides under the gate phase.
//  - Z/F loads and Z_new/F_new stores are nontemporal: 1.07 GB streams through
//    L2 exactly once, so it no longer evicts the high-reuse gate operands
//    (wm rows: 64x reuse, x rows: 1024x reuse) from L2.
__global__ __launch_bounds__(256) void rtrl_fused_kernel(
    const float* __restrict__ x,            // [B,I]
    const float* __restrict__ hidden_prev,  // [B,H]
    const float* __restrict__ Z_state,      // [B,H,I]
    const float* __restrict__ F_state,      // [B,H,I]
    const float* __restrict__ wz_state,     // [B,H]
    const float* __restrict__ wf_state,     // [B,H]
    const float* __restrict__ bz_state,     // [B,H]
    const float* __restrict__ bf_state,     // [B,H]
    const float* __restrict__ wm_z,         // [H,I]
    const float* __restrict__ wm_f,         // [H,I]
    const float* __restrict__ wv_z,         // [1,H]
    const float* __restrict__ wv_f,         // [1,H]
    const float* __restrict__ bias_z,       // [1,H]
    const float* __restrict__ bias_f,       // [1,H]
    float* __restrict__ out)
{
    const int row = blockIdx.x;        // 0 .. B*H-1 ; row = b*H + h
    const int b   = row >> 10;         // / 1024 (H)
    const int h   = row & 1023;        // % 1024
    const int t   = threadIdx.x;       // 0..255

    // ---- 0) issue ALL global loads up front, streaming (HBM) ones first
    const f32x4* __restrict__ Z4 = (const f32x4*)(Z_state + (size_t)row * II);
    const f32x4* __restrict__ F4 = (const f32x4*)(F_state + (size_t)row * II);
    const f32x4 zv = __builtin_nontemporal_load(&Z4[t]);
    const f32x4 fv = __builtin_nontemporal_load(&F4[t]);

    const f32x4* __restrict__ x4  = (const f32x4*)(x    + (size_t)b * II);
    const f32x4* __restrict__ az4 = (const f32x4*)(wm_z + (size_t)h * II);
    const f32x4* __restrict__ af4 = (const f32x4*)(wm_f + (size_t)h * II);

    const f32x4 xv = x4[t];            // reused later for the outer-product update
    const f32x4 az = az4[t];
    const f32x4 af = af4[t];

    // ---- 1) per-row gate dot products: out_z = x[b,:]·wm_z[h,:], same for f
    float pz = xv.x * az.x + xv.y * az.y + xv.z * az.z + xv.w * az.w;
    float pf = xv.x * af.x + xv.y * af.y + xv.z * af.z + xv.w * af.w;

    // wave (64-lane) reduction
    #pragma unroll
    for (int off = 32; off >= 1; off >>= 1) {
        pz += __shfl_down(pz, off, 64);
        pf += __shfl_down(pf, off, 64);
    }
    __shared__ float s_red[8];         // 4 waves x {z,f}
    const int wave = t >> 6;
    const int lane = t & 63;
    if (lane == 0) { s_red[wave] = pz; s_red[4 + wave] = pf; }
    __syncthreads();
    const float out_z = s_red[0] + s_red[1] + s_red[2] + s_red[3];
    const float out_f = s_red[4] + s_red[5] + s_red[6] + s_red[7];

    // ---- 2) gate math (every thread computes the same scalars — cheap)
    const float hp  = hidden_prev[row];
    const float wvz = wv_z[h];
    const float wvf = wv_f[h];

    const float z_pre = out_z + wvz * hp + bias_z[h];
    const float f_pre = out_f + wvf * hp + bias_f[h];
    const float zg = tanhf(z_pre);
    const float fg = 1.0f / (1.0f + expf(-f_pre));

    const float zf_tmp = (1.0f - fg) * (1.0f - zg * zg);
    const float fz_tmp = (hp - zg) * (1.0f - fg) * fg;
    const float common = fg + zf_tmp * wvz + fz_tmp * wvf;

    if (t == 0) {
        out[OFF_CELL + row] = hp * fg + (1.0f - fg) * zg;            // new_cell
        out[OFF_WZ   + row] = hp * zf_tmp + common * wz_state[row];  // wz_new
        out[OFF_WF   + row] = hp * fz_tmp + common * wf_state[row];  // wf_new
        out[OFF_BZ   + row] = zf_tmp + common * bz_state[row];       // bz_new
        out[OFF_BF   + row] = fz_tmp + common * bf_state[row];       // bf_new
    }

    // ---- 3) the HBM-bound streaming update (the actual roofline cost)
    f32x4* __restrict__ Zo = (f32x4*)(out + OFF_Z + (size_t)row * II);
    f32x4* __restrict__ Fo = (f32x4*)(out + OFF_F + (size_t)row * II);

    f32x4 zo, fo;
    zo.x = common * zv.x + zf_tmp * xv.x;
    zo.y = common * zv.y + zf_tmp * xv.y;
    zo.z = common * zv.z + zf_tmp * xv.z;
    zo.w = common * zv.w + zf_tmp * xv.w;
    fo.x = common * fv.x + fz_tmp * xv.x;
    fo.y = common * fv.y + fz_tmp * xv.y;
    fo.z = common * fv.z + fz_tmp * xv.z;
    fo.w = common * fv.w + fz_tmp * xv.w;

    __builtin_nontemporal_store(zo, &Zo[t]);
    __builtin_nontemporal_store(fo, &Fo[t]);
}

extern "C" void kernel_launch(void* const* d_in, const int* in_sizes, int n_in,
                              void* d_out, int out_size, void* d_ws, size_t ws_size,
                              hipStream_t stream) {
    const float* x           = (const float*)d_in[0];
    const float* hidden_prev = (const float*)d_in[1];
    const float* Z_state     = (const float*)d_in[2];
    const float* F_state     = (const float*)d_in[3];
    const float* wz_state    = (const float*)d_in[4];
    const float* wf_state    = (const float*)d_in[5];
    const float* bz_state    = (const float*)d_in[6];
    const float* bf_state    = (const float*)d_in[7];
    const float* wm_z        = (const float*)d_in[8];
    const float* wm_f        = (const float*)d_in[9];
    const float* wv_z        = (const float*)d_in[10];
    const float* wv_f        = (const float*)d_in[11];
    const float* bias_z      = (const float*)d_in[12];
    const float* bias_f      = (const float*)d_in[13];
    float* out = (float*)d_out;

    rtrl_fused_kernel<<<dim3(BB * HH), dim3(256), 0, stream>>>(
        x, hidden_prev, Z_state, F_state, wz_state, wf_state, bz_state, bf_state,
        wm_z, wm_f, wv_z, wv_f, bias_z, bias_f, out);
}